// Round 15
// baseline (612.302 us; speedup 1.0000x reference)
//
#include <hip/hip_runtime.h>

#define B_TOT 65536
#define T_STEPS 12
#define LOG2E 1.44269504088896f

typedef short bf16x8 __attribute__((ext_vector_type(8)));
typedef float f32x4 __attribute__((ext_vector_type(4)));

__device__ __forceinline__ unsigned short f2b(float f) {
  unsigned u = __float_as_uint(f);
  u += 0x7fffu + ((u >> 16) & 1u);
  return (unsigned short)(u >> 16);
}
__device__ __forceinline__ float b2f(unsigned short s) {
  return __uint_as_float(((unsigned)s) << 16);
}
__device__ __forceinline__ float lo2f(unsigned u) { return __uint_as_float(u << 16); }
__device__ __forceinline__ float hi2f(unsigned u) { return __uint_as_float(u & 0xffff0000u); }
__device__ __forceinline__ float fexp2(float x) { return __builtin_amdgcn_exp2f(x); }
__device__ __forceinline__ float frcp(float x) { return __builtin_amdgcn_rcpf(x); }
__device__ __forceinline__ f32x4 mfma16(bf16x8 a, bf16x8 b, f32x4 c) {
  return __builtin_amdgcn_mfma_f32_16x16x32_bf16(a, b, c, 0, 0, 0);
}
__device__ __forceinline__ bf16x8 ld8(const unsigned short* p) {
  return *reinterpret_cast<const bf16x8*>(p);
}

// ---------------------------------------------------------------------------
// Repack weights into MFMA B-fragment order (bf16) in workspace.
//   B-frag tile (nt,kc): lane l holds W[nt*16+(l&15)][kc*32+(l>>4)*8+e]
// ws layout (u16 elements) — footprint unchanged vs proven 167,936 B:
//   [0,     49152)  fragWhh   [24][4][64][8]   (W_hh 384x128)
//   [49152, 81920)  fragWat   [8][8][64][8]    (W_attn 128x256)
//   [81920, 82944)  fragWcomb [8 kc][4 row][4 rg][8 e]  compact 4 real rows of
//                   Wcomb = [Wmu;Wstd]@Wat (4x256); frag rows 4..15 zero-filled
//   [82944, 82952)  bcomb     4 x f32 = [Wmu;Wstd]@batn + [bmu;bstd]
// ---------------------------------------------------------------------------
__global__ void repack_weights(const float* __restrict__ Whh, const float* __restrict__ Wat,
                               const float* __restrict__ Wmu, const float* __restrict__ Wst,
                               const float* __restrict__ batn, const float* __restrict__ bmu,
                               const float* __restrict__ bstd, unsigned short* __restrict__ ws) {
  int idx = blockIdx.x * 256 + threadIdx.x;
  if (idx < 49152) {
    int e = idx & 7, ln = (idx >> 3) & 63, kc = (idx >> 9) & 3, nt = idx >> 11;
    int rr = nt * 16 + (ln & 15), kk = kc * 32 + (ln >> 4) * 8 + e;
    ws[idx] = f2b(Whh[rr * 128 + kk]);
  } else if (idx < 81920) {
    int j = idx - 49152;
    int e = j & 7, ln = (j >> 3) & 63, kc = (j >> 9) & 7, nt = j >> 12;
    int rr = nt * 16 + (ln & 15), kk = kc * 32 + (ln >> 4) * 8 + e;
    ws[idx] = f2b(Wat[rr * 256 + kk]);
  } else if (idx < 82944) {
    int j = idx - 81920;  // [kc][cj][rg][e]
    int e = j & 7, rg = (j >> 3) & 3, cj = (j >> 5) & 3, kc = j >> 7;
    int k = kc * 32 + rg * 8 + e;
    const float* wrow = (cj < 2) ? (Wmu + cj * 128) : (Wst + (cj - 2) * 128);
    float s = 0.f;
    for (int d = 0; d < 128; ++d) s += wrow[d] * Wat[d * 256 + k];
    ws[idx] = f2b(s);
  } else if (idx < 82948) {
    int cj = idx - 82944;
    const float* wrow = (cj < 2) ? (Wmu + cj * 128) : (Wst + (cj - 2) * 128);
    float s = (cj < 2) ? bmu[cj] : bstd[cj - 2];
    for (int d = 0; d < 128; ++d) s += wrow[d] * batn[d];
    ((float*)(ws + 82944))[cj] = s;
  }
}

// ---------------------------------------------------------------------------
// R15 = R14 with the LDS accounting bug fixed: s_pool was left at 14,592
// elements (R13's size) although hvT shrank to 4,096 — pushing total LDS to
// 83,456 B > 81,920 and halving occupancy (the whole R14 regression).
// s_pool is now 12,544 elements (hcat 8,448 + hvT 4,096; init zx 9,472 fits).
// Total LDS = 79,360 B -> 2 blocks/CU restored. No other changes.
// ---------------------------------------------------------------------------
__global__ __launch_bounds__(512, 4) void dec_main(
    const float* __restrict__ last_state, const float* __restrict__ enc,
    const float* __restrict__ zin, const float* __restrict__ fut,
    const float* __restrict__ Wdec, const float* __restrict__ bdec,
    const float* __restrict__ Wvel, const float* __restrict__ bvel,
    const float* __restrict__ Wih, const float* __restrict__ bih,
    const float* __restrict__ bhh, const float* __restrict__ batn,
    const unsigned short* __restrict__ fragW, float* __restrict__ out) {
  constexpr int HP = 136;   // s_h   [32][HP]
  constexpr int RP = 36;    // s_gxT [384][RP] transposed gx (row stride 72B)
  constexpr int ZXP = 296;  // staged zx [32][ZXP] (in pool)
  constexpr int HCP = 264;  // s_hcat[32][HCP]  (cols 0:128 hv, 128:256 ctx)
  constexpr int TVP = 16;   // s_hvT [2][128][TVP] exact-fit
  constexpr int HFP = 130;  // s_hf  [32][HFP] f32 carry

  __shared__ __align__(16) unsigned short s_gxT[384 * RP];
  __shared__ __align__(16) unsigned short s_h[32 * HP];
  __shared__ __align__(16) float s_hf[32 * HFP];
  __shared__ __align__(16) unsigned short s_pool[12544];  // init: zx(9472); steps: hcat(8448)+hvT(4096)
  __shared__ __align__(16) unsigned short s_attn[2 * 16 * 16];
  __shared__ __align__(16) float s_a[32 * 2];

  const int tid = threadIdx.x;
  const int lane = tid & 63;
  const int wv = tid >> 6;   // 0..7
  const int c = lane & 15;   // MFMA col / A-row lane index
  const int rg = lane >> 4;  // 0..3
  const int row0 = blockIdx.x * 32;

  // weight fragment tables in L2-resident workspace (read at use sites)
  const bf16x8* fWhh = (const bf16x8*)(fragW);
  const bf16x8* fWat = (const bf16x8*)(fragW + 49152);
  const unsigned short* fWcb = fragW + 81920;
  const float* bcb = (const float*)(fragW + 82944);

  const int colR = wv * 16 + c;  // 0..127
  const float wr0 = Wih[(colR)*290 + 288], wr1 = Wih[(colR)*290 + 289];
  const float wz0 = Wih[(colR + 128) * 290 + 288], wz1 = Wih[(colR + 128) * 290 + 289];
  const float wn0 = Wih[(colR + 256) * 290 + 288], wn1 = Wih[(colR + 256) * 290 + 289];
  const float bhr = bhh[colR], bhz = bhh[colR + 128], bhn = bhh[colR + 256];
  const float ba = batn[colR];

  // ---- stage zx = [enc | z] as bf16 into pool ----
#pragma unroll
  for (int i = 0; i < 4; ++i) {
    int f4 = tid + i * 512;  // 2048 float4 over 32x256
    int r = f4 >> 6, cc = (f4 & 63) << 2;
    const float4 v = *(const float4*)(enc + (size_t)(row0 + r) * 256 + cc);
    unsigned short* d = &s_pool[r * ZXP + cc];
    d[0] = f2b(v.x); d[1] = f2b(v.y); d[2] = f2b(v.z); d[3] = f2b(v.w);
  }
  if (tid < 256) {
    int r = tid >> 3, cc = (tid & 7) << 2;  // 256 float4 over 32x32
    const float4 v = *(const float4*)(zin + (size_t)(row0 + r) * 32 + cc);
    unsigned short* d = &s_pool[r * ZXP + 256 + cc];
    d[0] = f2b(v.x); d[1] = f2b(v.y); d[2] = f2b(v.z); d[3] = f2b(v.w);
  }
  // ---- a0 = last_state @ Wvel^T + bvel ----
  if (tid < 64) {
    int r = tid >> 1, j = tid & 1;
    float s = bvel[j];
#pragma unroll
    for (int k = 0; k < 6; ++k) s += last_state[(size_t)(row0 + r) * 6 + k] * Wvel[j * 6 + k];
    s_a[r * 2 + j] = s;
  }
  __syncthreads();

  // ---- init GEMM: gx_zx = zx@Wih[:, :288]^T + bih -> s_gxT (transposed);
  //      h0 = zx@Wdec^T + bdec -> s_h + s_hf ----
#pragma unroll 1
  for (int i = 0; i < 4; ++i) {
    const int nt = wv + 8 * i;  // 0..23: gx tiles; 24..31 (i==3): h0 tiles
    const bool isH = (i == 3);
    const int nrow = isH ? colR : (nt * 16 + c);
    const float* wp = isH ? (Wdec + (size_t)nrow * 288) : (Wih + (size_t)nrow * 290);
    f32x4 acc[2] = {{0.f, 0.f, 0.f, 0.f}, {0.f, 0.f, 0.f, 0.f}};
#pragma unroll 1
    for (int kc = 0; kc < 9; ++kc) {
      const float* bp = wp + kc * 32 + rg * 8;
      bf16x8 Bf;
#pragma unroll
      for (int e = 0; e < 8; ++e) Bf[e] = (short)f2b(bp[e]);
#pragma unroll
      for (int m = 0; m < 2; ++m) {
        bf16x8 A = ld8(&s_pool[(m * 16 + c) * ZXP + kc * 32 + rg * 8]);
        acc[m] = mfma16(A, Bf, acc[m]);
      }
    }
    if (isH) {
      const float bias = bdec[colR];
#pragma unroll
      for (int m = 0; m < 2; ++m)
#pragma unroll
        for (int r4 = 0; r4 < 4; ++r4) {
          int row = m * 16 + rg * 4 + r4;
          float v = acc[m][r4] + bias;
          s_h[row * HP + colR] = f2b(v);
          s_hf[row * HFP + colR] = v;
        }
    } else {
      const int colg = nt * 16 + c;  // 0..383 (gate-major column)
      const float bias = bih[colg];
#pragma unroll
      for (int m = 0; m < 2; ++m)
#pragma unroll
        for (int r4 = 0; r4 < 4; ++r4) {
          int row = m * 16 + rg * 4 + r4;
          s_gxT[colg * RP + row] = f2b(acc[m][r4] + bias);
        }
    }
  }
  __syncthreads();

  unsigned short* s_hcat = s_pool;        // [32][HCP]
  unsigned short* s_hvT = s_pool + 8448;  // [2][128][TVP]
  const int sq = wv >> 2;                 // sequence for attention phases (0..1)
  const int q4 = wv & 3;                  // quarter within sequence

#pragma unroll 1
  for (int t = 0; t < T_STEPS; ++t) {
    // ===== Phase A: gh GEMM + GRU gates -> hv =====
#pragma unroll 1
    for (int m = 0; m < 2; ++m) {
      f32x4 aR = {0.f, 0.f, 0.f, 0.f}, aZ = {0.f, 0.f, 0.f, 0.f}, aN = {0.f, 0.f, 0.f, 0.f};
#pragma unroll
      for (int kc = 0; kc < 4; ++kc) {
        bf16x8 A = ld8(&s_h[(m * 16 + c) * HP + kc * 32 + rg * 8]);
        aR = mfma16(A, fWhh[((wv)*4 + kc) * 64 + lane], aR);
        aZ = mfma16(A, fWhh[((wv + 8) * 4 + kc) * 64 + lane], aZ);
        aN = mfma16(A, fWhh[((wv + 16) * 4 + kc) * 64 + lane], aN);
      }
      // transposed-gx b64 reads: 4 rows per gate column in one uint2
      const uint2 gR2 = *(const uint2*)&s_gxT[colR * RP + m * 16 + rg * 4];
      const uint2 gZ2 = *(const uint2*)&s_gxT[(128 + colR) * RP + m * 16 + rg * 4];
      const uint2 gN2 = *(const uint2*)&s_gxT[(256 + colR) * RP + m * 16 + rg * 4];
      const float4 aLo = *(const float4*)&s_a[(m * 16 + rg * 4) * 2];
      const float4 aHi = *(const float4*)&s_a[(m * 16 + rg * 4) * 2 + 4];
      f32x4 hv4;
#pragma unroll
      for (int r4 = 0; r4 < 4; ++r4) {
        const int row = m * 16 + rg * 4 + r4;
        const float a0 = (r4 == 0) ? aLo.x : (r4 == 1) ? aLo.z : (r4 == 2) ? aHi.x : aHi.z;
        const float a1 = (r4 == 0) ? aLo.y : (r4 == 1) ? aLo.w : (r4 == 2) ? aHi.y : aHi.w;
        const float gxr = (r4 == 0) ? lo2f(gR2.x) : (r4 == 1) ? hi2f(gR2.x)
                         : (r4 == 2) ? lo2f(gR2.y) : hi2f(gR2.y);
        const float gxz = (r4 == 0) ? lo2f(gZ2.x) : (r4 == 1) ? hi2f(gZ2.x)
                         : (r4 == 2) ? lo2f(gZ2.y) : hi2f(gZ2.y);
        const float gxn = (r4 == 0) ? lo2f(gN2.x) : (r4 == 1) ? hi2f(gN2.x)
                         : (r4 == 2) ? lo2f(gN2.y) : hi2f(gN2.y);
        float gr = gxr + a0 * wr0 + a1 * wr1 + bhr + aR[r4];
        float gz = gxz + a0 * wz0 + a1 * wz1 + bhz + aZ[r4];
        float nx = gxn + a0 * wn0 + a1 * wn1;
        float nh = bhn + aN[r4];
        float rr = frcp(1.f + fexp2(-LOG2E * gr));
        float zz = frcp(1.f + fexp2(-LOG2E * gz));
        float xx = nx + rr * nh;
        xx = fminf(fmaxf(xx, -15.f), 15.f);
        float e2 = fexp2(2.f * LOG2E * xx);
        float nn = 1.f - 2.f * frcp(e2 + 1.f);
        float hv = (1.f - zz) * nn + zz * s_hf[row * HFP + colR];
        hv4[r4] = hv;
        s_hcat[row * HCP + colR] = f2b(hv);
      }
      // packed hvT write: rows rg*4..rg*4+3 contiguous in hvT inner dim, 8B-aligned
      unsigned p01 = (unsigned)f2b(hv4[0]) | ((unsigned)f2b(hv4[1]) << 16);
      unsigned p23 = (unsigned)f2b(hv4[2]) | ((unsigned)f2b(hv4[3]) << 16);
      uint2 pk; pk.x = p01; pk.y = p23;
      *(uint2*)&s_hvT[(m * 128 + colR) * TVP + rg * 4] = pk;
    }
    __syncthreads();

    // ===== Phase B1: score = hv@hv^T (symmetric); softmax split by q4 =====
    {
      f32x4 sc = {0.f, 0.f, 0.f, 0.f};
#pragma unroll
      for (int kc = 0; kc < 4; ++kc) {
        bf16x8 F = ld8(&s_hcat[(sq * 16 + c) * HCP + kc * 32 + rg * 8]);
        sc = mfma16(F, F, sc);
      }
      float v = (q4 == 0) ? sc[0] : (q4 == 1) ? sc[1] : (q4 == 2) ? sc[2] : sc[3];
      float mx = v;
#pragma unroll
      for (int d = 1; d < 16; d <<= 1) mx = fmaxf(mx, __shfl_xor(mx, d));
      float e = fexp2(LOG2E * (v - mx));
      float s = e;
#pragma unroll
      for (int d = 1; d < 16; d <<= 1) s += __shfl_xor(s, d);
      float p = e * frcp(s);
      s_attn[(sq * 16 + rg * 4 + q4) * 16 + c] = f2b(p);
    }
    __syncthreads();

    // ===== Phase B2: ctx = attn @ hv ; wave 6 prefetches next-step a =====
    {
      bf16x8 Aat = {0, 0, 0, 0, 0, 0, 0, 0};
      if (lane < 32) Aat = ld8(&s_attn[(sq * 16 + c) * 16 + rg * 8]);
#pragma unroll
      for (int i = 0; i < 2; ++i) {
        const int dt = q4 * 2 + i;
        bf16x8 Bv = {0, 0, 0, 0, 0, 0, 0, 0};
        if (lane < 32) Bv = ld8(&s_hvT[(sq * 128 + dt * 16 + c) * TVP + rg * 8]);
        f32x4 zz4 = {0.f, 0.f, 0.f, 0.f};
        f32x4 cx = mfma16(Aat, Bv, zz4);
#pragma unroll
        for (int r4 = 0; r4 < 4; ++r4)
          s_hcat[(sq * 16 + rg * 4 + r4) * HCP + 128 + dt * 16 + c] = f2b(cx[r4]);
      }
      if (wv == 6 && t + 1 < T_STEPS)
        s_a[lane] = fut[(size_t)t * B_TOT * 2 + (size_t)row0 * 2 + lane];
    }
    __syncthreads();

    // ===== Phase C: h = [hv|ctx] @ Wat^T + batn ; fused mu/std output
    // (waves 0 and 4, from s_hcat via Wcomb — stable all phase) =====
#pragma unroll 1
    for (int m = 0; m < 2; ++m) {
      const bool doOut = (wv == 0 && m == 0) || (wv == 4 && m == 1);
      f32x4 acc = {0.f, 0.f, 0.f, 0.f};
      f32x4 acc2 = {0.f, 0.f, 0.f, 0.f};
#pragma unroll
      for (int kc = 0; kc < 8; ++kc) {
        bf16x8 A = ld8(&s_hcat[(m * 16 + c) * HCP + kc * 32 + rg * 8]);
        acc = mfma16(A, fWat[(wv * 8 + kc) * 64 + lane], acc);
        if (doOut) {
          bf16x8 wf = {0, 0, 0, 0, 0, 0, 0, 0};
          if (c < 4) wf = ld8(&fWcb[((kc * 4 + c) * 4 + rg) * 8]);
          acc2 = mfma16(A, wf, acc2);
        }
      }
#pragma unroll
      for (int r4 = 0; r4 < 4; ++r4) {
        const int row = m * 16 + rg * 4 + r4;
        float v = acc[r4] + ba;
        s_h[row * HP + colR] = f2b(v);
        s_hf[row * HFP + colR] = v;
      }
      if (doOut && c < 4) {
#pragma unroll
        for (int r4 = 0; r4 < 4; ++r4) {
          const int gb = row0 + m * 16 + rg * 4 + r4;
          if (c < 2) {
            out[(size_t)t * B_TOT * 2 + (size_t)gb * 2 + c] = acc2[r4] + bcb[c];
          } else {
            out[(size_t)T_STEPS * B_TOT * 2 + (size_t)t * B_TOT * 2 + (size_t)gb * 2 + (c - 2)] =
                fexp2(0.72134752044448f * (acc2[r4] + bcb[c]));
          }
        }
      }
    }
    __syncthreads();
  }
}

extern "C" void kernel_launch(void* const* d_in, const int* in_sizes, int n_in,
                              void* d_out, int out_size, void* d_ws, size_t ws_size,
                              hipStream_t stream) {
  const float* last_state = (const float*)d_in[0];
  const float* enc = (const float*)d_in[1];
  const float* zin = (const float*)d_in[2];
  // d_in[3] seq_start_end: uniform arange(S)*P, unused; d_in[4] fut_obst: unused
  const float* fut = (const float*)d_in[5];
  const float* Wdec = (const float*)d_in[6];
  const float* bdec = (const float*)d_in[7];
  const float* Wvel = (const float*)d_in[8];
  const float* bvel = (const float*)d_in[9];
  const float* Wih = (const float*)d_in[10];
  const float* bih = (const float*)d_in[11];
  const float* Whh = (const float*)d_in[12];
  const float* bhh = (const float*)d_in[13];
  const float* Wat = (const float*)d_in[14];
  const float* batn = (const float*)d_in[15];
  const float* Wmu = (const float*)d_in[16];
  const float* bmu = (const float*)d_in[17];
  const float* Wst = (const float*)d_in[18];
  const float* bstd = (const float*)d_in[19];

  unsigned short* ws = (unsigned short*)d_ws;
  repack_weights<<<328, 256, 0, stream>>>(Whh, Wat, Wmu, Wst, batn, bmu, bstd, ws);
  dec_main<<<B_TOT / 32, 512, 0, stream>>>(last_state, enc, zin, fut, Wdec, bdec, Wvel, bvel,
                                           Wih, bih, bhh, batn, ws, (float*)d_out);
}

// Round 16
// 573.410 us; speedup vs baseline: 1.0678x; 1.0678x over previous
//
#include <hip/hip_runtime.h>

#define B_TOT 65536
#define T_STEPS 12
#define LOG2E 1.44269504088896f

typedef short bf16x8 __attribute__((ext_vector_type(8)));
typedef float f32x4 __attribute__((ext_vector_type(4)));

__device__ __forceinline__ unsigned short f2b(float f) {
  unsigned u = __float_as_uint(f);
  u += 0x7fffu + ((u >> 16) & 1u);
  return (unsigned short)(u >> 16);
}
__device__ __forceinline__ float b2f(unsigned short s) {
  return __uint_as_float(((unsigned)s) << 16);
}
__device__ __forceinline__ float lo2f(unsigned u) { return __uint_as_float(u << 16); }
__device__ __forceinline__ float hi2f(unsigned u) { return __uint_as_float(u & 0xffff0000u); }
__device__ __forceinline__ float fexp2(float x) { return __builtin_amdgcn_exp2f(x); }
__device__ __forceinline__ float frcp(float x) { return __builtin_amdgcn_rcpf(x); }
__device__ __forceinline__ f32x4 mfma16(bf16x8 a, bf16x8 b, f32x4 c) {
  return __builtin_amdgcn_mfma_f32_16x16x32_bf16(a, b, c, 0, 0, 0);
}
__device__ __forceinline__ bf16x8 ld8(const unsigned short* p) {
  return *reinterpret_cast<const bf16x8*>(p);
}

// ---------------------------------------------------------------------------
// Repack weights into MFMA B-fragment order (bf16) in workspace.
//   B-frag tile (nt,kc): lane l holds W[nt*16+(l&15)][kc*32+(l>>4)*8+e]
// ws layout (u16 elements) — footprint unchanged vs proven 167,936 B:
//   [0,     49152)  fragWhh   [24][4][64][8]   (W_hh 384x128)
//   [49152, 81920)  fragWat   [8][8][64][8]    (W_attn 128x256)
//   [81920, 82944)  fragWcomb [8 kc][4 row][4 rg][8 e]  compact 4 real rows of
//                   Wcomb = [Wmu;Wstd]@Wat (4x256); frag rows 4..15 zero-filled
//   [82944, 82952)  bcomb     4 x f32 = [Wmu;Wstd]@batn + [bmu;bstd]
// ---------------------------------------------------------------------------
__global__ void repack_weights(const float* __restrict__ Whh, const float* __restrict__ Wat,
                               const float* __restrict__ Wmu, const float* __restrict__ Wst,
                               const float* __restrict__ batn, const float* __restrict__ bmu,
                               const float* __restrict__ bstd, unsigned short* __restrict__ ws) {
  int idx = blockIdx.x * 256 + threadIdx.x;
  if (idx < 49152) {
    int e = idx & 7, ln = (idx >> 3) & 63, kc = (idx >> 9) & 3, nt = idx >> 11;
    int rr = nt * 16 + (ln & 15), kk = kc * 32 + (ln >> 4) * 8 + e;
    ws[idx] = f2b(Whh[rr * 128 + kk]);
  } else if (idx < 81920) {
    int j = idx - 49152;
    int e = j & 7, ln = (j >> 3) & 63, kc = (j >> 9) & 7, nt = j >> 12;
    int rr = nt * 16 + (ln & 15), kk = kc * 32 + (ln >> 4) * 8 + e;
    ws[idx] = f2b(Wat[rr * 256 + kk]);
  } else if (idx < 82944) {
    int j = idx - 81920;  // [kc][cj][rg][e]
    int e = j & 7, rg = (j >> 3) & 3, cj = (j >> 5) & 3, kc = j >> 7;
    int k = kc * 32 + rg * 8 + e;
    const float* wrow = (cj < 2) ? (Wmu + cj * 128) : (Wst + (cj - 2) * 128);
    float s = 0.f;
    for (int d = 0; d < 128; ++d) s += wrow[d] * Wat[d * 256 + k];
    ws[idx] = f2b(s);
  } else if (idx < 82948) {
    int cj = idx - 82944;
    const float* wrow = (cj < 2) ? (Wmu + cj * 128) : (Wst + (cj - 2) * 128);
    float s = (cj < 2) ? bmu[cj] : bstd[cj - 2];
    for (int d = 0; d < 128; ++d) s += wrow[d] * batn[d];
    ((float*)(ws + 82944))[cj] = s;
  }
}

// ---------------------------------------------------------------------------
// R16 = R15 with ONE change: __launch_bounds__(512,2) instead of (512,4).
// Evidence: the gxT kernel's natural register demand is 96 (R14, 1 blk/CU,
// zero spill, FETCH 43MB); under the (512,4) cap the allocator squeezed to
// 64 and spilled (R15: FETCH 405MB). (512,2) raises the cap so the allocator
// takes ~96; LDS (79,360B) remains the binding constraint at 2 blocks/CU
// (96 <= 128 VGPR keeps 4 waves/SIMD feasible). No code changes.
// ---------------------------------------------------------------------------
__global__ __launch_bounds__(512, 2) void dec_main(
    const float* __restrict__ last_state, const float* __restrict__ enc,
    const float* __restrict__ zin, const float* __restrict__ fut,
    const float* __restrict__ Wdec, const float* __restrict__ bdec,
    const float* __restrict__ Wvel, const float* __restrict__ bvel,
    const float* __restrict__ Wih, const float* __restrict__ bih,
    const float* __restrict__ bhh, const float* __restrict__ batn,
    const unsigned short* __restrict__ fragW, float* __restrict__ out) {
  constexpr int HP = 136;   // s_h   [32][HP]
  constexpr int RP = 36;    // s_gxT [384][RP] transposed gx (row stride 72B)
  constexpr int ZXP = 296;  // staged zx [32][ZXP] (in pool)
  constexpr int HCP = 264;  // s_hcat[32][HCP]  (cols 0:128 hv, 128:256 ctx)
  constexpr int TVP = 16;   // s_hvT [2][128][TVP] exact-fit
  constexpr int HFP = 130;  // s_hf  [32][HFP] f32 carry

  __shared__ __align__(16) unsigned short s_gxT[384 * RP];
  __shared__ __align__(16) unsigned short s_h[32 * HP];
  __shared__ __align__(16) float s_hf[32 * HFP];
  __shared__ __align__(16) unsigned short s_pool[12544];  // init: zx(9472); steps: hcat(8448)+hvT(4096)
  __shared__ __align__(16) unsigned short s_attn[2 * 16 * 16];
  __shared__ __align__(16) float s_a[32 * 2];

  const int tid = threadIdx.x;
  const int lane = tid & 63;
  const int wv = tid >> 6;   // 0..7
  const int c = lane & 15;   // MFMA col / A-row lane index
  const int rg = lane >> 4;  // 0..3
  const int row0 = blockIdx.x * 32;

  // weight fragment tables in L2-resident workspace (read at use sites)
  const bf16x8* fWhh = (const bf16x8*)(fragW);
  const bf16x8* fWat = (const bf16x8*)(fragW + 49152);
  const unsigned short* fWcb = fragW + 81920;
  const float* bcb = (const float*)(fragW + 82944);

  const int colR = wv * 16 + c;  // 0..127
  const float wr0 = Wih[(colR)*290 + 288], wr1 = Wih[(colR)*290 + 289];
  const float wz0 = Wih[(colR + 128) * 290 + 288], wz1 = Wih[(colR + 128) * 290 + 289];
  const float wn0 = Wih[(colR + 256) * 290 + 288], wn1 = Wih[(colR + 256) * 290 + 289];
  const float bhr = bhh[colR], bhz = bhh[colR + 128], bhn = bhh[colR + 256];
  const float ba = batn[colR];

  // ---- stage zx = [enc | z] as bf16 into pool ----
#pragma unroll
  for (int i = 0; i < 4; ++i) {
    int f4 = tid + i * 512;  // 2048 float4 over 32x256
    int r = f4 >> 6, cc = (f4 & 63) << 2;
    const float4 v = *(const float4*)(enc + (size_t)(row0 + r) * 256 + cc);
    unsigned short* d = &s_pool[r * ZXP + cc];
    d[0] = f2b(v.x); d[1] = f2b(v.y); d[2] = f2b(v.z); d[3] = f2b(v.w);
  }
  if (tid < 256) {
    int r = tid >> 3, cc = (tid & 7) << 2;  // 256 float4 over 32x32
    const float4 v = *(const float4*)(zin + (size_t)(row0 + r) * 32 + cc);
    unsigned short* d = &s_pool[r * ZXP + 256 + cc];
    d[0] = f2b(v.x); d[1] = f2b(v.y); d[2] = f2b(v.z); d[3] = f2b(v.w);
  }
  // ---- a0 = last_state @ Wvel^T + bvel ----
  if (tid < 64) {
    int r = tid >> 1, j = tid & 1;
    float s = bvel[j];
#pragma unroll
    for (int k = 0; k < 6; ++k) s += last_state[(size_t)(row0 + r) * 6 + k] * Wvel[j * 6 + k];
    s_a[r * 2 + j] = s;
  }
  __syncthreads();

  // ---- init GEMM: gx_zx = zx@Wih[:, :288]^T + bih -> s_gxT (transposed);
  //      h0 = zx@Wdec^T + bdec -> s_h + s_hf ----
#pragma unroll 1
  for (int i = 0; i < 4; ++i) {
    const int nt = wv + 8 * i;  // 0..23: gx tiles; 24..31 (i==3): h0 tiles
    const bool isH = (i == 3);
    const int nrow = isH ? colR : (nt * 16 + c);
    const float* wp = isH ? (Wdec + (size_t)nrow * 288) : (Wih + (size_t)nrow * 290);
    f32x4 acc[2] = {{0.f, 0.f, 0.f, 0.f}, {0.f, 0.f, 0.f, 0.f}};
#pragma unroll 1
    for (int kc = 0; kc < 9; ++kc) {
      const float* bp = wp + kc * 32 + rg * 8;
      bf16x8 Bf;
#pragma unroll
      for (int e = 0; e < 8; ++e) Bf[e] = (short)f2b(bp[e]);
#pragma unroll
      for (int m = 0; m < 2; ++m) {
        bf16x8 A = ld8(&s_pool[(m * 16 + c) * ZXP + kc * 32 + rg * 8]);
        acc[m] = mfma16(A, Bf, acc[m]);
      }
    }
    if (isH) {
      const float bias = bdec[colR];
#pragma unroll
      for (int m = 0; m < 2; ++m)
#pragma unroll
        for (int r4 = 0; r4 < 4; ++r4) {
          int row = m * 16 + rg * 4 + r4;
          float v = acc[m][r4] + bias;
          s_h[row * HP + colR] = f2b(v);
          s_hf[row * HFP + colR] = v;
        }
    } else {
      const int colg = nt * 16 + c;  // 0..383 (gate-major column)
      const float bias = bih[colg];
#pragma unroll
      for (int m = 0; m < 2; ++m)
#pragma unroll
        for (int r4 = 0; r4 < 4; ++r4) {
          int row = m * 16 + rg * 4 + r4;
          s_gxT[colg * RP + row] = f2b(acc[m][r4] + bias);
        }
    }
  }
  __syncthreads();

  unsigned short* s_hcat = s_pool;        // [32][HCP]
  unsigned short* s_hvT = s_pool + 8448;  // [2][128][TVP]
  const int sq = wv >> 2;                 // sequence for attention phases (0..1)
  const int q4 = wv & 3;                  // quarter within sequence

#pragma unroll 1
  for (int t = 0; t < T_STEPS; ++t) {
    // ===== Phase A: gh GEMM + GRU gates -> hv =====
#pragma unroll 1
    for (int m = 0; m < 2; ++m) {
      f32x4 aR = {0.f, 0.f, 0.f, 0.f}, aZ = {0.f, 0.f, 0.f, 0.f}, aN = {0.f, 0.f, 0.f, 0.f};
#pragma unroll
      for (int kc = 0; kc < 4; ++kc) {
        bf16x8 A = ld8(&s_h[(m * 16 + c) * HP + kc * 32 + rg * 8]);
        aR = mfma16(A, fWhh[((wv)*4 + kc) * 64 + lane], aR);
        aZ = mfma16(A, fWhh[((wv + 8) * 4 + kc) * 64 + lane], aZ);
        aN = mfma16(A, fWhh[((wv + 16) * 4 + kc) * 64 + lane], aN);
      }
      // transposed-gx b64 reads: 4 rows per gate column in one uint2
      const uint2 gR2 = *(const uint2*)&s_gxT[colR * RP + m * 16 + rg * 4];
      const uint2 gZ2 = *(const uint2*)&s_gxT[(128 + colR) * RP + m * 16 + rg * 4];
      const uint2 gN2 = *(const uint2*)&s_gxT[(256 + colR) * RP + m * 16 + rg * 4];
      const float4 aLo = *(const float4*)&s_a[(m * 16 + rg * 4) * 2];
      const float4 aHi = *(const float4*)&s_a[(m * 16 + rg * 4) * 2 + 4];
      f32x4 hv4;
#pragma unroll
      for (int r4 = 0; r4 < 4; ++r4) {
        const int row = m * 16 + rg * 4 + r4;
        const float a0 = (r4 == 0) ? aLo.x : (r4 == 1) ? aLo.z : (r4 == 2) ? aHi.x : aHi.z;
        const float a1 = (r4 == 0) ? aLo.y : (r4 == 1) ? aLo.w : (r4 == 2) ? aHi.y : aHi.w;
        const float gxr = (r4 == 0) ? lo2f(gR2.x) : (r4 == 1) ? hi2f(gR2.x)
                         : (r4 == 2) ? lo2f(gR2.y) : hi2f(gR2.y);
        const float gxz = (r4 == 0) ? lo2f(gZ2.x) : (r4 == 1) ? hi2f(gZ2.x)
                         : (r4 == 2) ? lo2f(gZ2.y) : hi2f(gZ2.y);
        const float gxn = (r4 == 0) ? lo2f(gN2.x) : (r4 == 1) ? hi2f(gN2.x)
                         : (r4 == 2) ? lo2f(gN2.y) : hi2f(gN2.y);
        float gr = gxr + a0 * wr0 + a1 * wr1 + bhr + aR[r4];
        float gz = gxz + a0 * wz0 + a1 * wz1 + bhz + aZ[r4];
        float nx = gxn + a0 * wn0 + a1 * wn1;
        float nh = bhn + aN[r4];
        float rr = frcp(1.f + fexp2(-LOG2E * gr));
        float zz = frcp(1.f + fexp2(-LOG2E * gz));
        float xx = nx + rr * nh;
        xx = fminf(fmaxf(xx, -15.f), 15.f);
        float e2 = fexp2(2.f * LOG2E * xx);
        float nn = 1.f - 2.f * frcp(e2 + 1.f);
        float hv = (1.f - zz) * nn + zz * s_hf[row * HFP + colR];
        hv4[r4] = hv;
        s_hcat[row * HCP + colR] = f2b(hv);
      }
      // packed hvT write: rows rg*4..rg*4+3 contiguous in hvT inner dim, 8B-aligned
      unsigned p01 = (unsigned)f2b(hv4[0]) | ((unsigned)f2b(hv4[1]) << 16);
      unsigned p23 = (unsigned)f2b(hv4[2]) | ((unsigned)f2b(hv4[3]) << 16);
      uint2 pk; pk.x = p01; pk.y = p23;
      *(uint2*)&s_hvT[(m * 128 + colR) * TVP + rg * 4] = pk;
    }
    __syncthreads();

    // ===== Phase B1: score = hv@hv^T (symmetric); softmax split by q4 =====
    {
      f32x4 sc = {0.f, 0.f, 0.f, 0.f};
#pragma unroll
      for (int kc = 0; kc < 4; ++kc) {
        bf16x8 F = ld8(&s_hcat[(sq * 16 + c) * HCP + kc * 32 + rg * 8]);
        sc = mfma16(F, F, sc);
      }
      float v = (q4 == 0) ? sc[0] : (q4 == 1) ? sc[1] : (q4 == 2) ? sc[2] : sc[3];
      float mx = v;
#pragma unroll
      for (int d = 1; d < 16; d <<= 1) mx = fmaxf(mx, __shfl_xor(mx, d));
      float e = fexp2(LOG2E * (v - mx));
      float s = e;
#pragma unroll
      for (int d = 1; d < 16; d <<= 1) s += __shfl_xor(s, d);
      float p = e * frcp(s);
      s_attn[(sq * 16 + rg * 4 + q4) * 16 + c] = f2b(p);
    }
    __syncthreads();

    // ===== Phase B2: ctx = attn @ hv ; wave 6 prefetches next-step a =====
    {
      bf16x8 Aat = {0, 0, 0, 0, 0, 0, 0, 0};
      if (lane < 32) Aat = ld8(&s_attn[(sq * 16 + c) * 16 + rg * 8]);
#pragma unroll
      for (int i = 0; i < 2; ++i) {
        const int dt = q4 * 2 + i;
        bf16x8 Bv = {0, 0, 0, 0, 0, 0, 0, 0};
        if (lane < 32) Bv = ld8(&s_hvT[(sq * 128 + dt * 16 + c) * TVP + rg * 8]);
        f32x4 zz4 = {0.f, 0.f, 0.f, 0.f};
        f32x4 cx = mfma16(Aat, Bv, zz4);
#pragma unroll
        for (int r4 = 0; r4 < 4; ++r4)
          s_hcat[(sq * 16 + rg * 4 + r4) * HCP + 128 + dt * 16 + c] = f2b(cx[r4]);
      }
      if (wv == 6 && t + 1 < T_STEPS)
        s_a[lane] = fut[(size_t)t * B_TOT * 2 + (size_t)row0 * 2 + lane];
    }
    __syncthreads();

    // ===== Phase C: h = [hv|ctx] @ Wat^T + batn ; fused mu/std output
    // (waves 0 and 4, from s_hcat via Wcomb — stable all phase) =====
#pragma unroll 1
    for (int m = 0; m < 2; ++m) {
      const bool doOut = (wv == 0 && m == 0) || (wv == 4 && m == 1);
      f32x4 acc = {0.f, 0.f, 0.f, 0.f};
      f32x4 acc2 = {0.f, 0.f, 0.f, 0.f};
#pragma unroll
      for (int kc = 0; kc < 8; ++kc) {
        bf16x8 A = ld8(&s_hcat[(m * 16 + c) * HCP + kc * 32 + rg * 8]);
        acc = mfma16(A, fWat[(wv * 8 + kc) * 64 + lane], acc);
        if (doOut) {
          bf16x8 wf = {0, 0, 0, 0, 0, 0, 0, 0};
          if (c < 4) wf = ld8(&fWcb[((kc * 4 + c) * 4 + rg) * 8]);
          acc2 = mfma16(A, wf, acc2);
        }
      }
#pragma unroll
      for (int r4 = 0; r4 < 4; ++r4) {
        const int row = m * 16 + rg * 4 + r4;
        float v = acc[r4] + ba;
        s_h[row * HP + colR] = f2b(v);
        s_hf[row * HFP + colR] = v;
      }
      if (doOut && c < 4) {
#pragma unroll
        for (int r4 = 0; r4 < 4; ++r4) {
          const int gb = row0 + m * 16 + rg * 4 + r4;
          if (c < 2) {
            out[(size_t)t * B_TOT * 2 + (size_t)gb * 2 + c] = acc2[r4] + bcb[c];
          } else {
            out[(size_t)T_STEPS * B_TOT * 2 + (size_t)t * B_TOT * 2 + (size_t)gb * 2 + (c - 2)] =
                fexp2(0.72134752044448f * (acc2[r4] + bcb[c]));
          }
        }
      }
    }
    __syncthreads();
  }
}

extern "C" void kernel_launch(void* const* d_in, const int* in_sizes, int n_in,
                              void* d_out, int out_size, void* d_ws, size_t ws_size,
                              hipStream_t stream) {
  const float* last_state = (const float*)d_in[0];
  const float* enc = (const float*)d_in[1];
  const float* zin = (const float*)d_in[2];
  // d_in[3] seq_start_end: uniform arange(S)*P, unused; d_in[4] fut_obst: unused
  const float* fut = (const float*)d_in[5];
  const float* Wdec = (const float*)d_in[6];
  const float* bdec = (const float*)d_in[7];
  const float* Wvel = (const float*)d_in[8];
  const float* bvel = (const float*)d_in[9];
  const float* Wih = (const float*)d_in[10];
  const float* bih = (const float*)d_in[11];
  const float* Whh = (const float*)d_in[12];
  const float* bhh = (const float*)d_in[13];
  const float* Wat = (const float*)d_in[14];
  const float* batn = (const float*)d_in[15];
  const float* Wmu = (const float*)d_in[16];
  const float* bmu = (const float*)d_in[17];
  const float* Wst = (const float*)d_in[18];
  const float* bstd = (const float*)d_in[19];

  unsigned short* ws = (unsigned short*)d_ws;
  repack_weights<<<328, 256, 0, stream>>>(Whh, Wat, Wmu, Wst, batn, bmu, bstd, ws);
  dec_main<<<B_TOT / 32, 512, 0, stream>>>(last_state, enc, zin, fut, Wdec, bdec, Wvel, bvel,
                                           Wih, bih, bhh, batn, ws, (float*)d_out);
}

// Round 17
// 436.560 us; speedup vs baseline: 1.4026x; 1.3135x over previous
//
#include <hip/hip_runtime.h>
#include <hip/hip_bf16.h>

#define B_TOT 65536
#define T_STEPS 12
#define LOG2E 1.44269504088896f

typedef short bf16x8 __attribute__((ext_vector_type(8)));
typedef float f32x4 __attribute__((ext_vector_type(4)));

__device__ __forceinline__ unsigned short f2b(float f) {
  __hip_bfloat16 h = __float2bfloat16(f);
  unsigned short u;
  __builtin_memcpy(&u, &h, 2);
  return u;
}
__device__ __forceinline__ unsigned cvt2n(float lo, float hi) {
  float2 v; v.x = lo; v.y = hi;
  __hip_bfloat162 h2 = __float22bfloat162_rn(v);
  unsigned u;
  __builtin_memcpy(&u, &h2, 4);
  return u;
}
__device__ __forceinline__ float b2f(unsigned short s) {
  return __uint_as_float(((unsigned)s) << 16);
}
__device__ __forceinline__ float fexp2(float x) { return __builtin_amdgcn_exp2f(x); }
__device__ __forceinline__ float frcp(float x) { return __builtin_amdgcn_rcpf(x); }
__device__ __forceinline__ f32x4 mfma16(bf16x8 a, bf16x8 b, f32x4 c) {
  return __builtin_amdgcn_mfma_f32_16x16x32_bf16(a, b, c, 0, 0, 0);
}
__device__ __forceinline__ bf16x8 ld8(const unsigned short* p) {
  return *reinterpret_cast<const bf16x8*>(p);
}

// ---------------------------------------------------------------------------
// Repack weights into MFMA B-fragment order (bf16) in workspace.
//   B-frag tile (nt,kc): lane l holds W[nt*16+(l&15)][kc*32+(l>>4)*8+e]
// ws layout (u16 elements) — footprint unchanged vs proven 167,936 B:
//   [0,     49152)  fragWhh   [24][4][64][8]   (W_hh 384x128)
//   [49152, 81920)  fragWat   [8][8][64][8]    (W_attn 128x256)
//   [81920, 82944)  fragWcomb [8 kc][4 row][4 rg][8 e]  compact 4 real rows of
//                   Wcomb = [Wmu;Wstd]@Wat (4x256); frag rows 4..15 zero-filled
//   [82944, 82952)  bcomb     4 x f32 = [Wmu;Wstd]@batn + [bmu;bstd]
// ---------------------------------------------------------------------------
__global__ void repack_weights(const float* __restrict__ Whh, const float* __restrict__ Wat,
                               const float* __restrict__ Wmu, const float* __restrict__ Wst,
                               const float* __restrict__ batn, const float* __restrict__ bmu,
                               const float* __restrict__ bstd, unsigned short* __restrict__ ws) {
  int idx = blockIdx.x * 256 + threadIdx.x;
  if (idx < 49152) {
    int e = idx & 7, ln = (idx >> 3) & 63, kc = (idx >> 9) & 3, nt = idx >> 11;
    int rr = nt * 16 + (ln & 15), kk = kc * 32 + (ln >> 4) * 8 + e;
    ws[idx] = f2b(Whh[rr * 128 + kk]);
  } else if (idx < 81920) {
    int j = idx - 49152;
    int e = j & 7, ln = (j >> 3) & 63, kc = (j >> 9) & 7, nt = j >> 12;
    int rr = nt * 16 + (ln & 15), kk = kc * 32 + (ln >> 4) * 8 + e;
    ws[idx] = f2b(Wat[rr * 256 + kk]);
  } else if (idx < 82944) {
    int j = idx - 81920;  // [kc][cj][rg][e]
    int e = j & 7, rg = (j >> 3) & 3, cj = (j >> 5) & 3, kc = j >> 7;
    int k = kc * 32 + rg * 8 + e;
    const float* wrow = (cj < 2) ? (Wmu + cj * 128) : (Wst + (cj - 2) * 128);
    float s = 0.f;
    for (int d = 0; d < 128; ++d) s += wrow[d] * Wat[d * 256 + k];
    ws[idx] = f2b(s);
  } else if (idx < 82948) {
    int cj = idx - 82944;
    const float* wrow = (cj < 2) ? (Wmu + cj * 128) : (Wst + (cj - 2) * 128);
    float s = (cj < 2) ? bmu[cj] : bstd[cj - 2];
    for (int d = 0; d < 128; ++d) s += wrow[d] * batn[d];
    ((float*)(ws + 82944))[cj] = s;
  }
}

// ---------------------------------------------------------------------------
// R17 = R13 (best passing, 472us; gxT/TVP16 abandoned — needs >128 total regs
// for spill-free codegen, incompatible with 2 blocks/CU) + two micro-changes:
//  (1) native packed bf16 conversion (__float22bfloat162_rn pairs ->
//      v_cvt_pk_bf16_f32, compiler-scheduled; replaces 5-op manual rounding).
//      Last untested R2-ghost component — isolated here.
//  (2) tanh via nn = 1 - 2*rcp(e2+1) (validated R14-16, 1 op fewer).
// Layout/sync/occupancy identical to R13.
// ---------------------------------------------------------------------------
__global__ __launch_bounds__(512, 4) void dec_main(
    const float* __restrict__ last_state, const float* __restrict__ enc,
    const float* __restrict__ zin, const float* __restrict__ fut,
    const float* __restrict__ Wdec, const float* __restrict__ bdec,
    const float* __restrict__ Wvel, const float* __restrict__ bvel,
    const float* __restrict__ Wih, const float* __restrict__ bih,
    const float* __restrict__ bhh, const float* __restrict__ batn,
    const unsigned short* __restrict__ fragW, float* __restrict__ out) {
  constexpr int HP = 136;   // s_h     [32][HP]
  constexpr int GXP = 388;  // s_gxzx  [32][GXP]
  constexpr int ZXP = 296;  // staged zx [32][ZXP] (in pool)
  constexpr int HCP = 264;  // s_hcat  [32][HCP]  (cols 0:128 hv, 128:256 ctx)
  constexpr int TVP = 24;   // s_hvT   [2][128][TVP]
  constexpr int HFP = 130;  // s_hf    [32][HFP] f32 carry (2-way banks)

  __shared__ __align__(16) unsigned short s_gxzx[32 * GXP];
  __shared__ __align__(16) unsigned short s_h[32 * HP];
  __shared__ __align__(16) float s_hf[32 * HFP];
  __shared__ __align__(16) unsigned short s_pool[14592];  // init: zx; steps: hcat(8448)+hvT(6144)
  __shared__ __align__(16) unsigned short s_attn[2 * 16 * 16];
  __shared__ __align__(16) float s_a[32 * 2];

  const int tid = threadIdx.x;
  const int lane = tid & 63;
  const int wv = tid >> 6;   // 0..7
  const int c = lane & 15;   // MFMA col / A-row lane index
  const int rg = lane >> 4;  // 0..3
  const int row0 = blockIdx.x * 32;

  // weight fragment tables in L2-resident workspace (read at use sites)
  const bf16x8* fWhh = (const bf16x8*)(fragW);
  const bf16x8* fWat = (const bf16x8*)(fragW + 49152);
  const unsigned short* fWcb = fragW + 81920;
  const float* bcb = (const float*)(fragW + 82944);

  const int colR = wv * 16 + c;  // 0..127
  const float wr0 = Wih[(colR)*290 + 288], wr1 = Wih[(colR)*290 + 289];
  const float wz0 = Wih[(colR + 128) * 290 + 288], wz1 = Wih[(colR + 128) * 290 + 289];
  const float wn0 = Wih[(colR + 256) * 290 + 288], wn1 = Wih[(colR + 256) * 290 + 289];
  const float bhr = bhh[colR], bhz = bhh[colR + 128], bhn = bhh[colR + 256];
  const float ba = batn[colR];

  // ---- stage zx = [enc | z] as bf16 into pool ----
#pragma unroll
  for (int i = 0; i < 4; ++i) {
    int f4 = tid + i * 512;  // 2048 float4 over 32x256
    int r = f4 >> 6, cc = (f4 & 63) << 2;
    const float4 v = *(const float4*)(enc + (size_t)(row0 + r) * 256 + cc);
    unsigned short* d = &s_pool[r * ZXP + cc];
    d[0] = f2b(v.x); d[1] = f2b(v.y); d[2] = f2b(v.z); d[3] = f2b(v.w);
  }
  if (tid < 256) {
    int r = tid >> 3, cc = (tid & 7) << 2;  // 256 float4 over 32x32
    const float4 v = *(const float4*)(zin + (size_t)(row0 + r) * 32 + cc);
    unsigned short* d = &s_pool[r * ZXP + 256 + cc];
    d[0] = f2b(v.x); d[1] = f2b(v.y); d[2] = f2b(v.z); d[3] = f2b(v.w);
  }
  // ---- a0 = last_state @ Wvel^T + bvel ----
  if (tid < 64) {
    int r = tid >> 1, j = tid & 1;
    float s = bvel[j];
#pragma unroll
    for (int k = 0; k < 6; ++k) s += last_state[(size_t)(row0 + r) * 6 + k] * Wvel[j * 6 + k];
    s_a[r * 2 + j] = s;
  }
  __syncthreads();

  // ---- init GEMM: gx_zx = zx@Wih[:, :288]^T + bih ; h0 = zx@Wdec^T + bdec ----
#pragma unroll 1
  for (int i = 0; i < 4; ++i) {
    const int nt = wv + 8 * i;  // 0..23: gx tiles; 24..31 (i==3): h0 tiles
    const bool isH = (i == 3);
    const int nrow = isH ? colR : (nt * 16 + c);
    const float* wp = isH ? (Wdec + (size_t)nrow * 288) : (Wih + (size_t)nrow * 290);
    f32x4 acc[2] = {{0.f, 0.f, 0.f, 0.f}, {0.f, 0.f, 0.f, 0.f}};
#pragma unroll 1
    for (int kc = 0; kc < 9; ++kc) {
      const float* bp = wp + kc * 32 + rg * 8;
      bf16x8 Bf;
#pragma unroll
      for (int e = 0; e < 8; ++e) Bf[e] = (short)f2b(bp[e]);
#pragma unroll
      for (int m = 0; m < 2; ++m) {
        bf16x8 A = ld8(&s_pool[(m * 16 + c) * ZXP + kc * 32 + rg * 8]);
        acc[m] = mfma16(A, Bf, acc[m]);
      }
    }
    if (isH) {
      const float bias = bdec[colR];
#pragma unroll
      for (int m = 0; m < 2; ++m)
#pragma unroll
        for (int r4 = 0; r4 < 4; ++r4) {
          int row = m * 16 + rg * 4 + r4;
          float v = acc[m][r4] + bias;
          s_h[row * HP + colR] = f2b(v);
          s_hf[row * HFP + colR] = v;
        }
    } else {
      const float bias = bih[nt * 16 + c];
#pragma unroll
      for (int m = 0; m < 2; ++m)
#pragma unroll
        for (int r4 = 0; r4 < 4; ++r4) {
          int row = m * 16 + rg * 4 + r4;
          s_gxzx[row * GXP + nt * 16 + c] = f2b(acc[m][r4] + bias);
        }
    }
  }
  __syncthreads();

  unsigned short* s_hcat = s_pool;        // [32][HCP]
  unsigned short* s_hvT = s_pool + 8448;  // [2][128][TVP]
  const int sq = wv >> 2;                 // sequence for attention phases (0..1)
  const int q4 = wv & 3;                  // quarter within sequence

#pragma unroll 1
  for (int t = 0; t < T_STEPS; ++t) {
    // ===== Phase A: gh GEMM + GRU gates -> hv =====
#pragma unroll 1
    for (int m = 0; m < 2; ++m) {
      f32x4 aR = {0.f, 0.f, 0.f, 0.f}, aZ = {0.f, 0.f, 0.f, 0.f}, aN = {0.f, 0.f, 0.f, 0.f};
#pragma unroll
      for (int kc = 0; kc < 4; ++kc) {
        bf16x8 A = ld8(&s_h[(m * 16 + c) * HP + kc * 32 + rg * 8]);
        aR = mfma16(A, fWhh[((wv)*4 + kc) * 64 + lane], aR);
        aZ = mfma16(A, fWhh[((wv + 8) * 4 + kc) * 64 + lane], aZ);
        aN = mfma16(A, fWhh[((wv + 16) * 4 + kc) * 64 + lane], aN);
      }
      const float4 aLo = *(const float4*)&s_a[(m * 16 + rg * 4) * 2];
      const float4 aHi = *(const float4*)&s_a[(m * 16 + rg * 4) * 2 + 4];
      f32x4 hv4;
#pragma unroll
      for (int r4 = 0; r4 < 4; ++r4) {
        const int row = m * 16 + rg * 4 + r4;
        const float a0 = (r4 == 0) ? aLo.x : (r4 == 1) ? aLo.z : (r4 == 2) ? aHi.x : aHi.z;
        const float a1 = (r4 == 0) ? aLo.y : (r4 == 1) ? aLo.w : (r4 == 2) ? aHi.y : aHi.w;
        float gr = b2f(s_gxzx[row * GXP + colR]) + a0 * wr0 + a1 * wr1 + bhr + aR[r4];
        float gz = b2f(s_gxzx[row * GXP + 128 + colR]) + a0 * wz0 + a1 * wz1 + bhz + aZ[r4];
        float nx = b2f(s_gxzx[row * GXP + 256 + colR]) + a0 * wn0 + a1 * wn1;
        float nh = bhn + aN[r4];
        float rr = frcp(1.f + fexp2(-LOG2E * gr));
        float zz = frcp(1.f + fexp2(-LOG2E * gz));
        float xx = nx + rr * nh;
        xx = fminf(fmaxf(xx, -15.f), 15.f);
        float e2 = fexp2(2.f * LOG2E * xx);
        float nn = 1.f - 2.f * frcp(e2 + 1.f);
        hv4[r4] = (1.f - zz) * nn + zz * s_hf[row * HFP + colR];
      }
      // packed conversions: 2x v_cvt_pk_bf16_f32 for 4 values
      unsigned p01 = cvt2n(hv4[0], hv4[1]), p23 = cvt2n(hv4[2], hv4[3]);
      const int hb = (m * 16 + rg * 4) * HCP + colR;
      s_hcat[hb] = (unsigned short)p01;
      s_hcat[hb + HCP] = (unsigned short)(p01 >> 16);
      s_hcat[hb + 2 * HCP] = (unsigned short)p23;
      s_hcat[hb + 3 * HCP] = (unsigned short)(p23 >> 16);
      uint2 pk; pk.x = p01; pk.y = p23;
      *(uint2*)&s_hvT[(m * 128 + colR) * TVP + rg * 4] = pk;
    }
    __syncthreads();

    // ===== Phase B1: score = hv@hv^T (symmetric); softmax split by q4 =====
    {
      f32x4 sc = {0.f, 0.f, 0.f, 0.f};
#pragma unroll
      for (int kc = 0; kc < 4; ++kc) {
        bf16x8 F = ld8(&s_hcat[(sq * 16 + c) * HCP + kc * 32 + rg * 8]);
        sc = mfma16(F, F, sc);
      }
      float v = (q4 == 0) ? sc[0] : (q4 == 1) ? sc[1] : (q4 == 2) ? sc[2] : sc[3];
      float mx = v;
#pragma unroll
      for (int d = 1; d < 16; d <<= 1) mx = fmaxf(mx, __shfl_xor(mx, d));
      float e = fexp2(LOG2E * (v - mx));
      float s = e;
#pragma unroll
      for (int d = 1; d < 16; d <<= 1) s += __shfl_xor(s, d);
      float p = e * frcp(s);
      s_attn[(sq * 16 + rg * 4 + q4) * 16 + c] = f2b(p);
    }
    __syncthreads();

    // ===== Phase B2: ctx = attn @ hv ; wave 6 prefetches next-step a =====
    {
      bf16x8 Aat = {0, 0, 0, 0, 0, 0, 0, 0};
      if (lane < 32) Aat = ld8(&s_attn[(sq * 16 + c) * 16 + rg * 8]);
#pragma unroll
      for (int i = 0; i < 2; ++i) {
        const int dt = q4 * 2 + i;
        bf16x8 Bv = {0, 0, 0, 0, 0, 0, 0, 0};
        if (lane < 32) Bv = ld8(&s_hvT[(sq * 128 + dt * 16 + c) * TVP + rg * 8]);
        f32x4 zz4 = {0.f, 0.f, 0.f, 0.f};
        f32x4 cx = mfma16(Aat, Bv, zz4);
        unsigned q01 = cvt2n(cx[0], cx[1]), q23 = cvt2n(cx[2], cx[3]);
        const int cb = (sq * 16 + rg * 4) * HCP + 128 + dt * 16 + c;
        s_hcat[cb] = (unsigned short)q01;
        s_hcat[cb + HCP] = (unsigned short)(q01 >> 16);
        s_hcat[cb + 2 * HCP] = (unsigned short)q23;
        s_hcat[cb + 3 * HCP] = (unsigned short)(q23 >> 16);
      }
      if (wv == 6 && t + 1 < T_STEPS)
        s_a[lane] = fut[(size_t)t * B_TOT * 2 + (size_t)row0 * 2 + lane];
    }
    __syncthreads();

    // ===== Phase C: h = [hv|ctx] @ Wat^T + batn ; fused mu/std output
    // (waves 0 and 4, from s_hcat via Wcomb — stable all phase) =====
#pragma unroll 1
    for (int m = 0; m < 2; ++m) {
      const bool doOut = (wv == 0 && m == 0) || (wv == 4 && m == 1);
      f32x4 acc = {0.f, 0.f, 0.f, 0.f};
      f32x4 acc2 = {0.f, 0.f, 0.f, 0.f};
#pragma unroll
      for (int kc = 0; kc < 8; ++kc) {
        bf16x8 A = ld8(&s_hcat[(m * 16 + c) * HCP + kc * 32 + rg * 8]);
        acc = mfma16(A, fWat[(wv * 8 + kc) * 64 + lane], acc);
        if (doOut) {
          bf16x8 wf = {0, 0, 0, 0, 0, 0, 0, 0};
          if (c < 4) wf = ld8(&fWcb[((kc * 4 + c) * 4 + rg) * 8]);
          acc2 = mfma16(A, wf, acc2);
        }
      }
      float v0 = acc[0] + ba, v1 = acc[1] + ba, v2 = acc[2] + ba, v3 = acc[3] + ba;
      const int hb = (m * 16 + rg * 4) * HP + colR;
      const int fb = (m * 16 + rg * 4) * HFP + colR;
      s_hf[fb] = v0; s_hf[fb + HFP] = v1; s_hf[fb + 2 * HFP] = v2; s_hf[fb + 3 * HFP] = v3;
      unsigned q01 = cvt2n(v0, v1), q23 = cvt2n(v2, v3);
      s_h[hb] = (unsigned short)q01;
      s_h[hb + HP] = (unsigned short)(q01 >> 16);
      s_h[hb + 2 * HP] = (unsigned short)q23;
      s_h[hb + 3 * HP] = (unsigned short)(q23 >> 16);
      if (doOut && c < 4) {
#pragma unroll
        for (int r4 = 0; r4 < 4; ++r4) {
          const int gb = row0 + m * 16 + rg * 4 + r4;
          if (c < 2) {
            out[(size_t)t * B_TOT * 2 + (size_t)gb * 2 + c] = acc2[r4] + bcb[c];
          } else {
            out[(size_t)T_STEPS * B_TOT * 2 + (size_t)t * B_TOT * 2 + (size_t)gb * 2 + (c - 2)] =
                fexp2(0.72134752044448f * (acc2[r4] + bcb[c]));
          }
        }
      }
    }
    __syncthreads();
  }
}

extern "C" void kernel_launch(void* const* d_in, const int* in_sizes, int n_in,
                              void* d_out, int out_size, void* d_ws, size_t ws_size,
                              hipStream_t stream) {
  const float* last_state = (const float*)d_in[0];
  const float* enc = (const float*)d_in[1];
  const float* zin = (const float*)d_in[2];
  // d_in[3] seq_start_end: uniform arange(S)*P, unused; d_in[4] fut_obst: unused
  const float* fut = (const float*)d_in[5];
  const float* Wdec = (const float*)d_in[6];
  const float* bdec = (const float*)d_in[7];
  const float* Wvel = (const float*)d_in[8];
  const float* bvel = (const float*)d_in[9];
  const float* Wih = (const float*)d_in[10];
  const float* bih = (const float*)d_in[11];
  const float* Whh = (const float*)d_in[12];
  const float* bhh = (const float*)d_in[13];
  const float* Wat = (const float*)d_in[14];
  const float* batn = (const float*)d_in[15];
  const float* Wmu = (const float*)d_in[16];
  const float* bmu = (const float*)d_in[17];
  const float* Wst = (const float*)d_in[18];
  const float* bstd = (const float*)d_in[19];

  unsigned short* ws = (unsigned short*)d_ws;
  repack_weights<<<328, 256, 0, stream>>>(Whh, Wat, Wmu, Wst, batn, bmu, bstd, ws);
  dec_main<<<B_TOT / 32, 512, 0, stream>>>(last_state, enc, zin, fut, Wdec, bdec, Wvel, bvel,
                                           Wih, bih, bhh, batn, ws, (float*)d_out);
}